// Round 8
// baseline (53.588 us; speedup 1.0000x reference)
//
#include <hip/hip_runtime.h>
#include <math.h>

#define NROWS 8192
#define NK    4096
#define NE    64
#define MAGIC 0x5A5A5A5Au

typedef _Float16 f16x8 __attribute__((ext_vector_type(8)));  // 4 VGPRs
typedef float    f32x4 __attribute__((ext_vector_type(4)));

// f32 -> (hi,lo) f16 pair, elementwise for 8 values in two float4s
#define CVT8(H, L, V0, V1)                                            \
  do {                                                                \
    H[0] = (_Float16)V0.x; L[0] = (_Float16)(V0.x - (float)H[0]);     \
    H[1] = (_Float16)V0.y; L[1] = (_Float16)(V0.y - (float)H[1]);     \
    H[2] = (_Float16)V0.z; L[2] = (_Float16)(V0.z - (float)H[2]);     \
    H[3] = (_Float16)V0.w; L[3] = (_Float16)(V0.w - (float)H[3]);     \
    H[4] = (_Float16)V1.x; L[4] = (_Float16)(V1.x - (float)H[4]);     \
    H[5] = (_Float16)V1.y; L[5] = (_Float16)(V1.y - (float)H[5]);     \
    H[6] = (_Float16)V1.z; L[6] = (_Float16)(V1.z - (float)H[6]);     \
    H[7] = (_Float16)V1.w; L[7] = (_Float16)(V1.w - (float)H[7]);     \
  } while (0)

// ---------------------------------------------------------------------------
// Single fused kernel. grid = 256 (all co-resident, 1/CU), block = 512 (8 wv).
//  Phase A: blocks 0..63 convert W slice -> fragment-linear f16 hi/lo
//           (layout verified rounds 4-7), release wflag[b]=MAGIC.
//  Phase B: every block issues its first x loads, then spins on 64 wflags.
//  Phase C: round-6 verified GEMM (wave wv = K-seg of 512, two 16-row M-tiles
//           sharing B-frags; full unroll + depth-2 x prefetch) -> LDS ->
//           8-way tree reduce -> softmax/top-2/renorm -> outputs; block
//           importance partial -> impp[e][blk], release pflag[blk].
//  Phase D: block 255 spins on 256 pflags, fixed-order importance sum -> aux.
// Poison/replay safety: flags are value-coded (MAGIC != 0xAA pattern); on
// replays stale-MAGIC fast-path reads bit-identical data (deterministic),
// first post-poison replay spins properly. No zeroing, no atomics needed.
// ---------------------------------------------------------------------------
__global__ __launch_bounds__(512, 2) void k_all(const float* __restrict__ x,
                                                const float* __restrict__ W,
                                                _Float16* __restrict__ Whi,
                                                _Float16* __restrict__ Wlo,
                                                unsigned* __restrict__ wflag,
                                                float* __restrict__ impp,
                                                unsigned* __restrict__ pflag,
                                                float* __restrict__ out) {
  __shared__ float plds[8][32][64];   // 64 KB partial logits
  __shared__ float logit[32][64];     // 8 KB reduced logits
  __shared__ float simp[8][64];       // 2 KB importance partials

  const int tid  = threadIdx.x;
  const int lane = tid & 63;
  const int wv   = __builtin_amdgcn_readfirstlane(tid >> 6);  // 0..7 = K-seg
  const int blk  = blockIdx.x;
  const int l15  = lane & 15;
  const int lhi  = lane >> 4;
  const int rbase = blk * 32;
  const int k0    = wv * 512;

  const float* __restrict__ xp0 = x + (size_t)(rbase + l15) * NK + k0 + lhi * 8;
  const float* __restrict__ xp1 = xp0 + (size_t)16 * NK;

  // ---- issue first two k-steps' x loads early (independent of W) ----
  float4 ca0 = *(const float4*)(xp0);
  float4 ca1 = *(const float4*)(xp0 + 4);
  float4 cb0 = *(const float4*)(xp1);
  float4 cb1 = *(const float4*)(xp1 + 4);
  float4 na0 = *(const float4*)(xp0 + 32);
  float4 na1 = *(const float4*)(xp0 + 36);
  float4 nb0 = *(const float4*)(xp1 + 32);
  float4 nb1 = *(const float4*)(xp1 + 36);

  // ---- Phase A: parallel W fragment conversion (blocks 0..63) ----
  if (blk < 64) {
    const int g    = blk * 512 + tid;        // fragment group 0..32767
    const int gl   = g & 63;
    const int gnt  = (g >> 6) & 3;
    const int gksg = g >> 8;
    const int e  = gnt * 16 + (gl & 15);
    const int kk = gksg * 32 + (gl >> 4) * 8;
    const float* wsrc = W + (size_t)e * NK + kk;
    const float4 w0 = *(const float4*)(wsrc);
    const float4 w1 = *(const float4*)(wsrc + 4);
    f16x8 hi, lo;
    CVT8(hi, lo, w0, w1);
    *(f16x8*)(Whi + (size_t)g * 8) = hi;
    *(f16x8*)(Wlo + (size_t)g * 8) = lo;
    __syncthreads();                       // all stores of this block issued+drained
    if (tid == 0)
      __hip_atomic_store(&wflag[blk], MAGIC, __ATOMIC_RELEASE,
                         __HIP_MEMORY_SCOPE_AGENT);
  }

  // ---- Phase B: wait for all W fragments ----
  if (wv == 0) {
    while (__hip_atomic_load(&wflag[lane], __ATOMIC_ACQUIRE,
                             __HIP_MEMORY_SCOPE_AGENT) != MAGIC)
      __builtin_amdgcn_s_sleep(2);
  }
  __syncthreads();

  // ---- Phase C: GEMM (round-6 structure, full unroll, depth-2 prefetch) ----
  f32x4 acc0[4], acc1[4];
#pragma unroll
  for (int nt = 0; nt < 4; ++nt) {
    acc0[nt] = (f32x4){0.f, 0.f, 0.f, 0.f};
    acc1[nt] = (f32x4){0.f, 0.f, 0.f, 0.f};
  }

#pragma unroll
  for (int ks = 0; ks < 16; ++ks) {   // 16 K-steps of 32
    f16x8 ah, al, bh, bl;
    CVT8(ah, al, ca0, ca1);
    CVT8(bh, bl, cb0, cb1);
    // rotate + prefetch ks+2
    ca0 = na0; ca1 = na1; cb0 = nb0; cb1 = nb1;
    if (ks + 2 < 16) {
      na0 = *(const float4*)(xp0 + (ks + 2) * 32);
      na1 = *(const float4*)(xp0 + (ks + 2) * 32 + 4);
      nb0 = *(const float4*)(xp1 + (ks + 2) * 32);
      nb1 = *(const float4*)(xp1 + (ks + 2) * 32 + 4);
    }

    const int gk = wv * 16 + ks;      // global 32-k group, 0..127
    const size_t boff = ((size_t)(gk * 4) * 64 + lane) * 8;
    f16x8 wh_[4], wl_[4];
#pragma unroll
    for (int nt = 0; nt < 4; ++nt) {
      wh_[nt] = *(const f16x8*)(Whi + boff + nt * 512);
      wl_[nt] = *(const f16x8*)(Wlo + boff + nt * 512);
    }
#pragma unroll
    for (int nt = 0; nt < 4; ++nt) {
      acc0[nt] = __builtin_amdgcn_mfma_f32_16x16x32_f16(ah, wh_[nt], acc0[nt], 0, 0, 0);
      acc1[nt] = __builtin_amdgcn_mfma_f32_16x16x32_f16(bh, wh_[nt], acc1[nt], 0, 0, 0);
    }
#pragma unroll
    for (int nt = 0; nt < 4; ++nt) {
      acc0[nt] = __builtin_amdgcn_mfma_f32_16x16x32_f16(ah, wl_[nt], acc0[nt], 0, 0, 0);
      acc1[nt] = __builtin_amdgcn_mfma_f32_16x16x32_f16(bh, wl_[nt], acc1[nt], 0, 0, 0);
    }
#pragma unroll
    for (int nt = 0; nt < 4; ++nt) {
      acc0[nt] = __builtin_amdgcn_mfma_f32_16x16x32_f16(al, wh_[nt], acc0[nt], 0, 0, 0);
      acc1[nt] = __builtin_amdgcn_mfma_f32_16x16x32_f16(bl, wh_[nt], acc1[nt], 0, 0, 0);
    }
  }

  // ---- epilogue to LDS: D col = lane&15, row = (lane>>4)*4 + reg ----
#pragma unroll
  for (int nt = 0; nt < 4; ++nt)
#pragma unroll
    for (int r = 0; r < 4; ++r) {
      plds[wv][lhi * 4 + r][nt * 16 + l15]      = acc0[nt][r];
      plds[wv][16 + lhi * 4 + r][nt * 16 + l15] = acc1[nt][r];
    }
  __syncthreads();

  // ---- 8-seg pairwise tree reduce (round-6 tree, bit-identical) ----
#pragma unroll
  for (int i = 0; i < 4; ++i) {
    const int elem = tid + i * 512;      // 0..2047
    const int row  = elem >> 6;
    const int col  = elem & 63;
    const float s01 = plds[0][row][col] + plds[1][row][col];
    const float s23 = plds[2][row][col] + plds[3][row][col];
    const float s45 = plds[4][row][col] + plds[5][row][col];
    const float s67 = plds[6][row][col] + plds[7][row][col];
    logit[row][col] = ((s01 + s23) + (s45 + s67));
  }
  __syncthreads();

  // ---- softmax/top-2/renorm: wave wv handles rows wv*4 .. +4 ----
  float impacc = 0.f;
#pragma unroll 1
  for (int i = 0; i < 4; ++i) {
    const int rl  = wv * 4 + i;
    const int row = rbase + rl;
    const float lg = logit[rl][lane];

    float m = lg;
#pragma unroll
    for (int d = 1; d < 64; d <<= 1) m = fmaxf(m, __shfl_xor(m, d));
    float p = expf(lg - m);
    float s = p;
#pragma unroll
    for (int d = 1; d < 64; d <<= 1) s += __shfl_xor(s, d);
    const float gate = p / s;
    impacc += gate;

    const unsigned long long key =
        ((unsigned long long)__float_as_uint(gate) << 32) | (unsigned)(63 - lane);
    unsigned long long k1 = key;
#pragma unroll
    for (int d = 1; d < 64; d <<= 1) {
      unsigned long long o = __shfl_xor(k1, d);
      if (o > k1) k1 = o;
    }
    const int e1 = 63 - (int)(k1 & 63ull);
    unsigned long long k2 = (lane == e1) ? 0ull : key;
#pragma unroll
    for (int d = 1; d < 64; d <<= 1) {
      unsigned long long o = __shfl_xor(k2, d);
      if (o > k2) k2 = o;
    }
    const int e2 = 63 - (int)(k2 & 63ull);

    if (lane == 0) {
      const float g1 = __uint_as_float((unsigned)(k1 >> 32));
      const float g2 = __uint_as_float((unsigned)(k2 >> 32));
      const float tt  = expf(g2 - g1);          // g1 >= g2
      const float inv = 1.f / (1.f + tt);
      out[(size_t)row * 2]     = inv;
      out[(size_t)row * 2 + 1] = tt * inv;
      out[(size_t)NROWS * 2 + row * 2]     = (float)e1;
      out[(size_t)NROWS * 2 + row * 2 + 1] = (float)e2;
    }
  }
  simp[wv][lane] = impacc;
  __syncthreads();

  // ---- block importance partial -> impp[e][blk]; release pflag ----
  if (tid < NE) {
    const float v = (((simp[0][tid] + simp[1][tid]) + (simp[2][tid] + simp[3][tid])) +
                     ((simp[4][tid] + simp[5][tid]) + (simp[6][tid] + simp[7][tid])));
    impp[(size_t)tid * 256 + blk] = v;
  }
  __syncthreads();                     // impp stores drained
  if (tid == 0)
    __hip_atomic_store(&pflag[blk], MAGIC, __ATOMIC_RELEASE,
                       __HIP_MEMORY_SCOPE_AGENT);

  // ---- Phase D: block 255 aggregates importance, computes aux ----
  if (blk == 255) {
    if (wv == 0) {
#pragma unroll
      for (int q = 0; q < 4; ++q)
        while (__hip_atomic_load(&pflag[lane + q * 64], __ATOMIC_ACQUIRE,
                                 __HIP_MEMORY_SCOPE_AGENT) != MAGIC)
          __builtin_amdgcn_s_sleep(2);
    }
    __syncthreads();
    if (tid < NE) {
      const float* pp = impp + (size_t)tid * 256;
      float a0 = 0.f, a1 = 0.f, a2 = 0.f, a3 = 0.f;
#pragma unroll 4
      for (int b = 0; b < 256; b += 4) {
        a0 += pp[b]; a1 += pp[b + 1]; a2 += pp[b + 2]; a3 += pp[b + 3];
      }
      const float v = (a0 + a1) + (a2 + a3);
      float s = v;
#pragma unroll
      for (int d = 1; d < 64; d <<= 1) s += __shfl_xor(s, d);
      const float mean = s / 64.f;
      const float dv = v - mean;
      float sq = dv * dv;
#pragma unroll
      for (int d = 1; d < 64; d <<= 1) sq += __shfl_xor(sq, d);
      const float stdv = sqrtf(sq / 63.f);  // unbiased (E-1)
      const float r = stdv / (mean + 1e-6f);
      if (tid == 0) out[(size_t)NROWS * 4] = r * r;  // d_out[32768]
    }
  }
}

// ---------------------------------------------------------------------------
extern "C" void kernel_launch(void* const* d_in, const int* in_sizes, int n_in,
                              void* d_out, int out_size, void* d_ws, size_t ws_size,
                              hipStream_t stream) {
  const float* x = (const float*)d_in[0];
  const float* W = (const float*)d_in[1];
  float* out = (float*)d_out;
  char* ws = (char*)d_ws;
  _Float16* Whi   = (_Float16*)(ws);                 // 512 KB
  _Float16* Wlo   = (_Float16*)(ws + 524288);        // 512 KB
  float*    impp  = (float*)  (ws + 1048576);        // 64 KB  impp[e][blk]
  unsigned* wflag = (unsigned*)(ws + 1114112);       // 256 B
  unsigned* pflag = (unsigned*)(ws + 1114624);       // 1 KB

  hipLaunchKernelGGL(k_all, dim3(256), dim3(512), 0, stream,
                     x, W, Whi, Wlo, wflag, impp, pflag, out);
}

// Round 9
// 47.889 us; speedup vs baseline: 1.1190x; 1.1190x over previous
//
#include <hip/hip_runtime.h>
#include <math.h>

#define NROWS 8192
#define NK    4096
#define NE    64
#define NWV   8     // waves per block = K segments of 512

typedef _Float16 f16x8 __attribute__((ext_vector_type(8)));  // 4 VGPRs
typedef float    f32x4 __attribute__((ext_vector_type(4)));

// f32 -> (hi,lo) f16 pair, elementwise for 8 values in two float4s
#define CVT8(H, L, V0, V1)                                            \
  do {                                                                \
    H[0] = (_Float16)V0.x; L[0] = (_Float16)(V0.x - (float)H[0]);     \
    H[1] = (_Float16)V0.y; L[1] = (_Float16)(V0.y - (float)H[1]);     \
    H[2] = (_Float16)V0.z; L[2] = (_Float16)(V0.z - (float)H[2]);     \
    H[3] = (_Float16)V0.w; L[3] = (_Float16)(V0.w - (float)H[3]);     \
    H[4] = (_Float16)V1.x; L[4] = (_Float16)(V1.x - (float)H[4]);     \
    H[5] = (_Float16)V1.y; L[5] = (_Float16)(V1.y - (float)H[5]);     \
    H[6] = (_Float16)V1.z; L[6] = (_Float16)(V1.z - (float)H[6]);     \
    H[7] = (_Float16)V1.w; L[7] = (_Float16)(V1.w - (float)H[7]);     \
  } while (0)

// ---------------------------------------------------------------------------
// Kernel 0: arrange W into MFMA-fragment-linear f16 hi/lo arrays + zero imp.
// Element ((ksg*4 + nt)*64 + lane)*8 + j holds
//   f16( W[nt*16 + (lane&15)][ksg*32 + (lane>>4)*8 + j] ), ksg = 0..127.
// (verified rounds 4-8, absmax 0)
// ---------------------------------------------------------------------------
__global__ __launch_bounds__(256) void k_prep(const float* __restrict__ W,
                                              _Float16* __restrict__ Whi,
                                              _Float16* __restrict__ Wlo,
                                              float* __restrict__ imp) {
  const int idx = blockIdx.x * 256 + threadIdx.x;   // 0 .. 262143
  if (idx < NE) imp[idx] = 0.f;
  const int j    = idx & 7;
  const int lane = (idx >> 3) & 63;
  const int nt   = (idx >> 9) & 3;
  const int ksg  = idx >> 11;                        // 0..127
  const int e = nt * 16 + (lane & 15);
  const int k = ksg * 32 + (lane >> 4) * 8 + j;
  const float w = W[(size_t)e * NK + k];
  const _Float16 wh = (_Float16)w;
  const _Float16 wl = (_Float16)(w - (float)wh);
  Whi[idx] = wh;
  Wlo[idx] = wl;
}

// ---------------------------------------------------------------------------
// Kernel 1 (FUSED, round-6 structure): 32 rows x full K per block; GEMM
// partials -> LDS -> 8-way tree reduce -> softmax/top-2/renorm -> outputs.
// grid = 256 (1 block/CU), block = 512 (8 waves).
// ROUND-9 FIX: amdgpu_waves_per_eu(2,2) — round 8 showed the allocator chose
// 64 VGPRs (occupancy-greedy) and serialized all loads (MfmaUtil 5%,
// VALUBusy 6%: pure latency stall). Capping max waves/EU at 2 (all we can
// use anyway: grid = 1 block/CU) raises the register budget to 256 so the
// depth-1 W prefetch + depth-2 x prefetch below actually stay in flight.
// ---------------------------------------------------------------------------
__global__ __launch_bounds__(512)
__attribute__((amdgpu_waves_per_eu(2, 2)))
void k_fused(const float* __restrict__ x,
             const _Float16* __restrict__ Whi,
             const _Float16* __restrict__ Wlo,
             float* __restrict__ out,
             float* __restrict__ imp) {
  __shared__ float plds[NWV][32][64];   // 64 KB partial logits
  __shared__ float logit[32][64];       // 8 KB reduced logits
  __shared__ float simp[NWV][64];       // 2 KB importance partials

  const int tid  = threadIdx.x;
  const int lane = tid & 63;
  const int wv   = __builtin_amdgcn_readfirstlane(tid >> 6);  // 0..7 = K-seg
  const int l15  = lane & 15;
  const int lhi  = lane >> 4;
  const int rbase = blockIdx.x * 32;
  const int k0    = wv * 512;

  const float* __restrict__ xp0 = x + (size_t)(rbase + l15) * NK + k0 + lhi * 8;
  const float* __restrict__ xp1 = xp0 + (size_t)16 * NK;
  const _Float16* __restrict__ whp = Whi + ((size_t)(wv * 16 * 4) * 64 + lane) * 8;
  const _Float16* __restrict__ wlp = Wlo + ((size_t)(wv * 16 * 4) * 64 + lane) * 8;

  f32x4 acc0[4], acc1[4];
#pragma unroll
  for (int nt = 0; nt < 4; ++nt) {
    acc0[nt] = (f32x4){0.f, 0.f, 0.f, 0.f};
    acc1[nt] = (f32x4){0.f, 0.f, 0.f, 0.f};
  }

  // ---- prologue: x for ks=0,1 and W-frags for ks=0 ----
  float4 ca0 = *(const float4*)(xp0);
  float4 ca1 = *(const float4*)(xp0 + 4);
  float4 cb0 = *(const float4*)(xp1);
  float4 cb1 = *(const float4*)(xp1 + 4);
  float4 na0 = *(const float4*)(xp0 + 32);
  float4 na1 = *(const float4*)(xp0 + 36);
  float4 nb0 = *(const float4*)(xp1 + 32);
  float4 nb1 = *(const float4*)(xp1 + 36);
  f16x8 whc[4], wlc[4], whn[4], wln[4];
#pragma unroll
  for (int nt = 0; nt < 4; ++nt) {
    whc[nt] = *(const f16x8*)(whp + nt * 512);
    wlc[nt] = *(const f16x8*)(wlp + nt * 512);
  }

#pragma unroll
  for (int ks = 0; ks < 16; ++ks) {   // 16 K-steps of 32 (fully unrolled)
    // prefetch next W-frags (depth 1)
    if (ks < 15) {
      const size_t nb_ = (size_t)(ks + 1) * 2048;   // 4*64*8 per k-step
#pragma unroll
      for (int nt = 0; nt < 4; ++nt) {
        whn[nt] = *(const f16x8*)(whp + nb_ + nt * 512);
        wln[nt] = *(const f16x8*)(wlp + nb_ + nt * 512);
      }
    }
    // prefetch x (depth 2)
    float4 pa0, pa1, pb0, pb1;
    if (ks + 2 < 16) {
      pa0 = *(const float4*)(xp0 + (ks + 2) * 32);
      pa1 = *(const float4*)(xp0 + (ks + 2) * 32 + 4);
      pb0 = *(const float4*)(xp1 + (ks + 2) * 32);
      pb1 = *(const float4*)(xp1 + (ks + 2) * 32 + 4);
    }

    f16x8 ah, al, bh, bl;
    CVT8(ah, al, ca0, ca1);
    CVT8(bh, bl, cb0, cb1);

#pragma unroll
    for (int nt = 0; nt < 4; ++nt) {
      acc0[nt] = __builtin_amdgcn_mfma_f32_16x16x32_f16(ah, whc[nt], acc0[nt], 0, 0, 0);
      acc1[nt] = __builtin_amdgcn_mfma_f32_16x16x32_f16(bh, whc[nt], acc1[nt], 0, 0, 0);
    }
#pragma unroll
    for (int nt = 0; nt < 4; ++nt) {
      acc0[nt] = __builtin_amdgcn_mfma_f32_16x16x32_f16(ah, wlc[nt], acc0[nt], 0, 0, 0);
      acc1[nt] = __builtin_amdgcn_mfma_f32_16x16x32_f16(bh, wlc[nt], acc1[nt], 0, 0, 0);
    }
#pragma unroll
    for (int nt = 0; nt < 4; ++nt) {
      acc0[nt] = __builtin_amdgcn_mfma_f32_16x16x32_f16(al, whc[nt], acc0[nt], 0, 0, 0);
      acc1[nt] = __builtin_amdgcn_mfma_f32_16x16x32_f16(bl, whc[nt], acc1[nt], 0, 0, 0);
    }

    // rotate (static indices: loop fully unrolled)
    ca0 = na0; ca1 = na1; cb0 = nb0; cb1 = nb1;
    na0 = pa0; na1 = pa1; nb0 = pb0; nb1 = pb1;
#pragma unroll
    for (int nt = 0; nt < 4; ++nt) { whc[nt] = whn[nt]; wlc[nt] = wln[nt]; }
  }

  // ---- epilogue to LDS: D col = lane&15, row = (lane>>4)*4 + reg ----
#pragma unroll
  for (int nt = 0; nt < 4; ++nt)
#pragma unroll
    for (int r = 0; r < 4; ++r) {
      plds[wv][lhi * 4 + r][nt * 16 + l15]      = acc0[nt][r];
      plds[wv][16 + lhi * 4 + r][nt * 16 + l15] = acc1[nt][r];
    }
  __syncthreads();

  // ---- 8-seg pairwise tree reduce (round-6 tree, bit-identical) ----
#pragma unroll
  for (int i = 0; i < 4; ++i) {
    const int elem = tid + i * 512;      // 0..2047
    const int row  = elem >> 6;
    const int col  = elem & 63;
    const float s01 = plds[0][row][col] + plds[1][row][col];
    const float s23 = plds[2][row][col] + plds[3][row][col];
    const float s45 = plds[4][row][col] + plds[5][row][col];
    const float s67 = plds[6][row][col] + plds[7][row][col];
    logit[row][col] = ((s01 + s23) + (s45 + s67));
  }
  __syncthreads();

  // ---- softmax/top-2/renorm: wave wv handles rows wv*4 .. +4 ----
  float impacc = 0.f;
#pragma unroll 1
  for (int i = 0; i < 4; ++i) {
    const int rl  = wv * 4 + i;
    const int row = rbase + rl;
    const float lg = logit[rl][lane];

    float m = lg;
#pragma unroll
    for (int d = 1; d < 64; d <<= 1) m = fmaxf(m, __shfl_xor(m, d));
    float p = expf(lg - m);
    float s = p;
#pragma unroll
    for (int d = 1; d < 64; d <<= 1) s += __shfl_xor(s, d);
    const float gate = p / s;
    impacc += gate;

    const unsigned long long key =
        ((unsigned long long)__float_as_uint(gate) << 32) | (unsigned)(63 - lane);
    unsigned long long k1 = key;
#pragma unroll
    for (int d = 1; d < 64; d <<= 1) {
      unsigned long long o = __shfl_xor(k1, d);
      if (o > k1) k1 = o;
    }
    const int e1 = 63 - (int)(k1 & 63ull);
    unsigned long long k2 = (lane == e1) ? 0ull : key;
#pragma unroll
    for (int d = 1; d < 64; d <<= 1) {
      unsigned long long o = __shfl_xor(k2, d);
      if (o > k2) k2 = o;
    }
    const int e2 = 63 - (int)(k2 & 63ull);

    if (lane == 0) {
      const float g1 = __uint_as_float((unsigned)(k1 >> 32));
      const float g2 = __uint_as_float((unsigned)(k2 >> 32));
      const float tt  = expf(g2 - g1);          // g1 >= g2
      const float inv = 1.f / (1.f + tt);
      out[(size_t)row * 2]     = inv;
      out[(size_t)row * 2 + 1] = tt * inv;
      out[(size_t)NROWS * 2 + row * 2]     = (float)e1;
      out[(size_t)NROWS * 2 + row * 2 + 1] = (float)e2;
    }
  }
  simp[wv][lane] = impacc;
  __syncthreads();

  if (tid < NE) {
    const float v = (((simp[0][tid] + simp[1][tid]) + (simp[2][tid] + simp[3][tid])) +
                     ((simp[4][tid] + simp[5][tid]) + (simp[6][tid] + simp[7][tid])));
    atomicAdd(&imp[tid], v);
  }
}

// ---------------------------------------------------------------------------
// Kernel 2: aux loss from importance vector (1 wave).
// ---------------------------------------------------------------------------
__global__ void k_aux(const float* __restrict__ imp, float* __restrict__ out) {
  const int lane = threadIdx.x;  // 64 threads
  const float v = imp[lane];
  float s = v;
#pragma unroll
  for (int d = 1; d < 64; d <<= 1) s += __shfl_xor(s, d);
  const float mean = s / 64.f;
  const float dv = v - mean;
  float sq = dv * dv;
#pragma unroll
  for (int d = 1; d < 64; d <<= 1) sq += __shfl_xor(sq, d);
  const float stdv = sqrtf(sq / 63.f);  // unbiased (E-1)
  const float r = stdv / (mean + 1e-6f);
  if (lane == 0) out[(size_t)NROWS * 4] = r * r;  // d_out[32768]
}

// ---------------------------------------------------------------------------
extern "C" void kernel_launch(void* const* d_in, const int* in_sizes, int n_in,
                              void* d_out, int out_size, void* d_ws, size_t ws_size,
                              hipStream_t stream) {
  const float* x = (const float*)d_in[0];
  const float* W = (const float*)d_in[1];
  float* out  = (float*)d_out;
  _Float16* Whi = (_Float16*)d_ws;                 // 512 KB
  _Float16* Wlo = Whi + (size_t)NE * NK;           // 512 KB
  float* imp  = (float*)(Wlo + (size_t)NE * NK);   // 64 f32

  hipLaunchKernelGGL(k_prep,  dim3(1024), dim3(256), 0, stream, W, Whi, Wlo, imp);
  hipLaunchKernelGGL(k_fused, dim3(256),  dim3(512), 0, stream, x, Whi, Wlo, out, imp);
  hipLaunchKernelGGL(k_aux,   dim3(1),    dim3(64),  0, stream, imp, out);
}